// Round 4
// baseline (282.224 us; speedup 1.0000x reference)
//
#include <hip/hip_runtime.h>
#include <hip/hip_bf16.h>

#define B_N     1024
#define IN_DIM  165
#define EMB_D   150
#define FEAT    315
#define H0_W    325
#define MB_OUT  10
#define MB_INT  50
#define MROW    64

typedef __attribute__((ext_vector_type(8))) short short8;
typedef __attribute__((ext_vector_type(4))) float f32x4;

__device__ __forceinline__ ushort f2bf(float f) {
    uint u = __float_as_uint(f);
    return (ushort)((u + 0x7fffu + ((u >> 16) & 1u)) >> 16);
}
__device__ __forceinline__ uint pack_split(float v) {
    ushort h = f2bf(v);
    float hf = __uint_as_float((uint)h << 16);
    ushort l = f2bf(v - hf);
    return (uint)h | ((uint)l << 16);
}
__device__ __forceinline__ float unpack_split(uint u) {
    return __uint_as_float(u << 16) + __uint_as_float(u & 0xffff0000u);
}

// ---------------- build x = concat(ts, emb[cond]) packed -----------------------
__global__ __launch_bounds__(320) void build_x_kernel(
    const float* __restrict__ ts, const int* __restrict__ cond,
    const float* __restrict__ emb, uint* __restrict__ h0p)
{
    int b = blockIdx.x, t = threadIdx.x;
    float v;
    if (t < IN_DIM)      v = ts[b * IN_DIM + t];
    else if (t < FEAT)   v = emb[cond[b] * EMB_D + (t - IN_DIM)];
    else return;
    h0p[b * H0_W + t] = pack_split(v);
}

// ---------------- MFMA bf16-split GEMM with optional K-split -------------------
template<int EPI, bool FAST>
__global__ __launch_bounds__(256) void gemm_mfma(
    const uint*  __restrict__ Ap, const float* __restrict__ Bw,
    const float* __restrict__ bias, void* __restrict__ Cout,
    int N, int K, int lda, int ldb, int ldc,
    int kIterTotal, int Ks, float* __restrict__ Pout)
{
    __shared__ ushort Ah[64 * 32], Al[64 * 32], Bh[64 * 32], Bl[64 * 32];

    const int t    = threadIdx.x;
    const int bm   = blockIdx.y << 6;
    const int bn   = blockIdx.x << 6;
    const int wid  = t >> 6, lane = t & 63;
    const int wm   = (wid >> 1) << 5, wn = (wid & 1) << 5;
    const int lm   = lane & 15, lc = lane >> 4;

    const int ar  = t >> 2, ac = t & 3;
    const int bn2 = t & 63, bk = t >> 6;

    const int z   = blockIdx.z;
    const int it0 = z * Ks;
    const int nIt = min(Ks, kIterTotal - it0);

    const int aw = ar  * 32 + ((ac ^ (ar  & 3)) << 3);
    const int bw = bn2 * 32 + ((bk ^ (bn2 & 3)) << 3);
    const int sw = (lc ^ (lm & 3)) << 3;
    const int a0 = (wm + lm)      * 32 + sw;
    const int a1 = (wm + 16 + lm) * 32 + sw;
    const int b0 = (wn + lm)      * 32 + sw;
    const int b1 = (wn + 16 + lm) * 32 + sw;

    uint  curA[8], nxtA[8];
    float curB[8], nxtB[8];

    auto loadA = [&](int k0, uint* dst) {
        const uint* p = Ap + (bm + ar) * lda + k0 + (ac << 3);
        if (FAST) {
            uint4 v0 = *(const uint4*)p;
            uint4 v1 = *(const uint4*)(p + 4);
            dst[0] = v0.x; dst[1] = v0.y; dst[2] = v0.z; dst[3] = v0.w;
            dst[4] = v1.x; dst[5] = v1.y; dst[6] = v1.z; dst[7] = v1.w;
        } else {
            int kb = k0 + (ac << 3);
            #pragma unroll
            for (int j = 0; j < 8; ++j)
                dst[j] = (kb + j < K) ? p[j] : 0u;
        }
    };
    auto loadB = [&](int k0, float* dst) {
        int kb = k0 + (bk << 3);
        const float* p = Bw + kb * ldb + bn + bn2;
        if (FAST) {
            #pragma unroll
            for (int j = 0; j < 8; ++j) dst[j] = p[j * ldb];
        } else {
            bool cok = (bn + bn2) < N;
            #pragma unroll
            for (int j = 0; j < 8; ++j)
                dst[j] = (cok && (kb + j) < K) ? p[j * ldb] : 0.f;
        }
    };

    f32x4 acc[2][2] = {};

    loadA(it0 << 5, curA);
    loadB(it0 << 5, curB);

    for (int it = 0; it < nIt; ++it) {
        short8 vah, val, vbh, vbl;
        #pragma unroll
        for (int j = 0; j < 8; ++j) {
            vah[j] = (short)(curA[j] & 0xffffu);
            val[j] = (short)(curA[j] >> 16);
            float v = curB[j];
            ushort h = f2bf(v);
            float hf = __uint_as_float((uint)h << 16);
            vbh[j] = (short)h;
            vbl[j] = (short)f2bf(v - hf);
        }
        __syncthreads();
        *(short8*)&Ah[aw] = vah;
        *(short8*)&Al[aw] = val;
        *(short8*)&Bh[bw] = vbh;
        *(short8*)&Bl[bw] = vbl;
        __syncthreads();

        if (it + 1 < nIt) {
            loadA((it0 + it + 1) << 5, nxtA);
            loadB((it0 + it + 1) << 5, nxtB);
        }

        short8 fah0 = *(const short8*)&Ah[a0];
        short8 fah1 = *(const short8*)&Ah[a1];
        short8 fal0 = *(const short8*)&Al[a0];
        short8 fal1 = *(const short8*)&Al[a1];
        short8 fbh0 = *(const short8*)&Bh[b0];
        short8 fbh1 = *(const short8*)&Bh[b1];
        short8 fbl0 = *(const short8*)&Bl[b0];
        short8 fbl1 = *(const short8*)&Bl[b1];

        acc[0][0] = __builtin_amdgcn_mfma_f32_16x16x32_bf16(fah0, fbh0, acc[0][0], 0, 0, 0);
        acc[0][1] = __builtin_amdgcn_mfma_f32_16x16x32_bf16(fah0, fbh1, acc[0][1], 0, 0, 0);
        acc[1][0] = __builtin_amdgcn_mfma_f32_16x16x32_bf16(fah1, fbh0, acc[1][0], 0, 0, 0);
        acc[1][1] = __builtin_amdgcn_mfma_f32_16x16x32_bf16(fah1, fbh1, acc[1][1], 0, 0, 0);
        acc[0][0] = __builtin_amdgcn_mfma_f32_16x16x32_bf16(fah0, fbl0, acc[0][0], 0, 0, 0);
        acc[0][1] = __builtin_amdgcn_mfma_f32_16x16x32_bf16(fah0, fbl1, acc[0][1], 0, 0, 0);
        acc[1][0] = __builtin_amdgcn_mfma_f32_16x16x32_bf16(fah1, fbl0, acc[1][0], 0, 0, 0);
        acc[1][1] = __builtin_amdgcn_mfma_f32_16x16x32_bf16(fah1, fbl1, acc[1][1], 0, 0, 0);
        acc[0][0] = __builtin_amdgcn_mfma_f32_16x16x32_bf16(fal0, fbh0, acc[0][0], 0, 0, 0);
        acc[0][1] = __builtin_amdgcn_mfma_f32_16x16x32_bf16(fal0, fbh1, acc[0][1], 0, 0, 0);
        acc[1][0] = __builtin_amdgcn_mfma_f32_16x16x32_bf16(fal1, fbh0, acc[1][0], 0, 0, 0);
        acc[1][1] = __builtin_amdgcn_mfma_f32_16x16x32_bf16(fal1, fbh1, acc[1][1], 0, 0, 0);

        #pragma unroll
        for (int j = 0; j < 8; ++j) { curA[j] = nxtA[j]; curB[j] = nxtB[j]; }
    }

    if (gridDim.z > 1) {
        float* P = Pout + (size_t)z * B_N * N;
        #pragma unroll
        for (int mi = 0; mi < 2; ++mi)
        #pragma unroll
        for (int ni = 0; ni < 2; ++ni)
        #pragma unroll
        for (int r = 0; r < 4; ++r) {
            int row = bm + wm + mi * 16 + lc * 4 + r;
            int col = bn + wn + ni * 16 + lm;
            if (col < N) P[row * N + col] = acc[mi][ni][r];
        }
        return;
    }

    #pragma unroll
    for (int mi = 0; mi < 2; ++mi)
    #pragma unroll
    for (int ni = 0; ni < 2; ++ni)
    #pragma unroll
    for (int r = 0; r < 4; ++r) {
        int row = bm + wm + mi * 16 + lc * 4 + r;
        int col = bn + wn + ni * 16 + lm;
        float v = acc[mi][ni][r];
        if (EPI == 0) {
            v += bias[col];
            v = (v > 0.f) ? v : 0.2f * v;
            ((uint*)Cout)[row * ldc + col] = pack_split(v);
        } else {
            if (col < N) {
                int o = col / MB_INT, kk = col - o * MB_INT;
                ((float*)Cout)[(o * B_N + row) * MROW + kk] = v;
            }
        }
    }
}

// ---------------- split-K epilogues -------------------------------------------
__global__ __launch_bounds__(256) void epi_pack_kernel(
    const float* __restrict__ P, const float* __restrict__ bias,
    uint* __restrict__ outp, int n4, int S)
{
    const int c4 = blockIdx.x * 64 + (threadIdx.x & 63);
    const int r  = blockIdx.y * 4 + (threadIdx.x >> 6);
    const int idx = r * n4 + c4;
    const float4* P4 = (const float4*)P;
    float4 v = P4[idx];
    for (int s = 1; s < S; ++s) {
        float4 w = P4[(size_t)s * B_N * n4 + idx];
        v.x += w.x; v.y += w.y; v.z += w.z; v.w += w.w;
    }
    float4 bb = ((const float4*)bias)[c4];
    v.x += bb.x; v.y += bb.y; v.z += bb.z; v.w += bb.w;
    v.x = (v.x > 0.f) ? v.x : 0.2f * v.x;
    v.y = (v.y > 0.f) ? v.y : 0.2f * v.y;
    v.z = (v.z > 0.f) ? v.z : 0.2f * v.z;
    v.w = (v.w > 0.f) ? v.w : 0.2f * v.w;
    uint4 o;
    o.x = pack_split(v.x); o.y = pack_split(v.y);
    o.z = pack_split(v.z); o.w = pack_split(v.w);
    ((uint4*)outp)[idx] = o;
}

__global__ __launch_bounds__(256) void epi_m2_kernel(
    const float* __restrict__ P, float* __restrict__ M2, int S)
{
    int i = blockIdx.x * 256 + threadIdx.x;   // < 1024*500
    if (i >= B_N * 500) return;
    int r = i / 500, c = i - r * 500;
    float v = P[i];
    for (int s = 1; s < S; ++s) v += P[(size_t)s * B_N * 500 + i];
    int o = c / MB_INT, k = c - o * MB_INT;
    M2[(o * B_N + r) * MROW + k] = v;
}

// ---------------- symmetric pairwise L1 + exp (rotation pairing) ---------------
// Unordered tile pairs (At <= Bt), 16 tiles of 64 rows. Lane i owns A-row i in
// registers; step s loads B-row (i+s)&63 straight from global (L1), computes
// e = exp(-L1dist), accumulates own row sum, and forwards e to the column
// owner with ONE __shfl. Steps split in half over blockIdx.z for occupancy.
// Block = 4 waves sharing one B-chunk (At = Ag*4+wid). part has 32 writer
// slots per (chunk,o): writer w = partner_tile*2 + shalf, each written once.
__global__ __launch_bounds__(256) void pairwise_kernel(
    const float* __restrict__ M2, float* __restrict__ part)
{
    const int x = blockIdx.x, o = blockIdx.y, h = blockIdx.z;
    int Bt = 0, Ag = 0;
    {
        int acc = 0;
        for (int bt = 0; bt < 16; ++bt) {
            int nb = (bt >> 2) + 1;
            if (x < acc + nb) { Bt = bt; Ag = x - acc; break; }
            acc += nb;
        }
    }
    const int wid = threadIdx.x >> 6, lane = threadIdx.x & 63;
    const int At = Ag * 4 + wid;
    if (At > Bt) return;                       // idle wave (no barriers here)
    const bool diag = (At == Bt);

    // own row -> registers (cols 50..63 are pad: never read)
    float m[50];
    const float* Arow = M2 + (o * B_N + At * 64 + lane) * MROW;
    #pragma unroll
    for (int j = 0; j < 12; ++j) {
        float4 v = ((const float4*)Arow)[j];
        m[j*4+0] = v.x; m[j*4+1] = v.y; m[j*4+2] = v.z; m[j*4+3] = v.w;
    }
    { float2 v = *(const float2*)(Arow + 48); m[48] = v.x; m[49] = v.y; }

    const float* Bbase = M2 + (o * B_N + Bt * 64) * MROW;

    const int sBeg = (diag && h == 0) ? 1 : h * 32;
    const int sEnd = (h == 0) ? 32 : 64;

    float rowacc = (diag && h == 0) ? 1.f : 0.f;   // self term exp(0)=1
    float colacc = 0.f;

    for (int s = sBeg; s < sEnd; ++s) {
        const int j = (lane + s) & 63;
        const float* q = Bbase + j * MROW;
        float t0 = 0.f, t1 = 0.f, t2 = 0.f, t3 = 0.f;
        #pragma unroll
        for (int j4 = 0; j4 < 12; ++j4) {
            float4 v = ((const float4*)q)[j4];
            t0 += fabsf(m[j4*4+0] - v.x);
            t1 += fabsf(m[j4*4+1] - v.y);
            t2 += fabsf(m[j4*4+2] - v.z);
            t3 += fabsf(m[j4*4+3] - v.w);
        }
        {
            float2 v = *(const float2*)(q + 48);
            t0 += fabsf(m[48] - v.x);
            t1 += fabsf(m[49] - v.y);
        }
        float e = __expf(-((t0 + t1) + (t2 + t3)));
        rowacc += e;
        if (!diag) {
            int src = (lane - s) & 63;             // lane that computed col 'lane'
            colacc += __shfl(e, src);
        }
    }

    part[((Bt * 2 + h) * MB_OUT + o) * B_N + At * 64 + lane] = rowacc;
    if (!diag)
        part[((At * 2 + h) * MB_OUT + o) * B_N + Bt * 64 + lane] = colacc;
}

// ---------------- reduce 32 partials into h0p[:, 315:325] ----------------------
__global__ __launch_bounds__(256) void mb_reduce_kernel(
    const float* __restrict__ part, uint* __restrict__ h0p)
{
    int i = blockIdx.x * 256 + threadIdx.x;
    if (i < MB_OUT * B_N) {
        int o = i / B_N, b = i - o * B_N;
        float s = 0.f;
        #pragma unroll
        for (int w = 0; w < 32; ++w)
            s += part[(w * MB_OUT + o) * B_N + b];
        h0p[b * H0_W + FEAT + o] = pack_split(s);
    }
}

// ---------------- final layer: sigmoid(h4 @ W5 + b5) ---------------------------
__global__ __launch_bounds__(256) void final_kernel(
    const uint* __restrict__ h4p, const float* __restrict__ W5,
    const float* __restrict__ b5, float* __restrict__ out)
{
    const int wave = threadIdx.x >> 6;
    const int lane = threadIdx.x & 63;
    const int row  = blockIdx.x * 4 + wave;

    const uint4  h = ((const uint4*)(h4p + row * 256))[lane];
    const float4 w = ((const float4*)W5)[lane];
    float s = unpack_split(h.x) * w.x + unpack_split(h.y) * w.y
            + unpack_split(h.z) * w.z + unpack_split(h.w) * w.w;
    #pragma unroll
    for (int off = 32; off > 0; off >>= 1)
        s += __shfl_xor(s, off);
    if (lane == 0) {
        float z = s + b5[0];
        out[row] = 1.f / (1.f + __expf(-z));
    }
}

// ---------------- launch -------------------------------------------------------
extern "C" void kernel_launch(void* const* d_in, const int* in_sizes, int n_in,
                              void* d_out, int out_size, void* d_ws, size_t ws_size,
                              hipStream_t stream)
{
    const float* ts   = (const float*)d_in[0];
    const int*   cond = (const int*)  d_in[1];
    const float* emb  = (const float*)d_in[2];
    const float* T    = (const float*)d_in[3];
    const float* W1   = (const float*)d_in[4];
    const float* b1   = (const float*)d_in[5];
    const float* W2   = (const float*)d_in[6];
    const float* b2   = (const float*)d_in[7];
    const float* W3   = (const float*)d_in[8];
    const float* b3   = (const float*)d_in[9];
    const float* W4   = (const float*)d_in[10];
    const float* b4   = (const float*)d_in[11];
    const float* W5   = (const float*)d_in[12];
    const float* b5   = (const float*)d_in[13];
    float* out = (float*)d_out;

    // workspace (4-byte units)
    uint*  h0p  = (uint*)d_ws;             // 332800
    float* M2   = (float*)(h0p + 332800);  // 655360
    float* part = M2 + 655360;             // 32*10*1024 = 327680
    uint*  h1p  = (uint*)(part + 327680);  // 1572864
    uint*  h2p  = h1p + 1572864;           // 1048576
    uint*  h3p  = (uint*)M2;               // alias (524288 <= 655360)
    uint*  h4p  = h1p;                     // alias
    const size_t baseU = 332800 + 655360 + 327680 + 1572864 + 1048576; // 3937280
    size_t capU = (ws_size / 4 > baseU) ? ws_size / 4 - baseU : 0;
    float* Pbuf = (float*)((uint*)d_ws + baseU);

    auto fits = [&](int s, int N) { return (size_t)s * B_N * N <= capU; };
    const int ST = fits(2, 500)  ? 2 : 1;
    const int S1 = fits(2, 1536) ? 2 : 1;
    const int S2 = fits(3, 1024) ? 3 : (fits(2, 1024) ? 2 : 1);
    const int S3 = fits(4, 512)  ? 4 : (fits(2, 512)  ? 2 : 1);
    const int S4 = fits(4, 256)  ? 4 : (fits(2, 256)  ? 2 : 1);

    build_x_kernel<<<B_N, 320, 0, stream>>>(ts, cond, emb, h0p);

    // M = x @ T (K=315, N=500)
    {
        int kit = 10, ks = (kit + ST - 1) / ST;
        dim3 g(8, 16, ST);
        gemm_mfma<1,false><<<g, 256, 0, stream>>>(h0p, T, nullptr, M2,
                                                  500, FEAT, H0_W, 500, 0, kit, ks, Pbuf);
        if (ST > 1)
            epi_m2_kernel<<<(B_N * 500 + 255) / 256, 256, 0, stream>>>(Pbuf, M2, ST);
    }

    { dim3 g(40, MB_OUT, 2); pairwise_kernel<<<g, 256, 0, stream>>>(M2, part); }
    mb_reduce_kernel<<<(MB_OUT * B_N + 255) / 256, 256, 0, stream>>>(part, h0p);

    auto runL = [&](const uint* in, const float* W, const float* bia, uint* outp,
                    int N, int K, int lda, int S, bool fast) {
        int kit = (K + 31) >> 5, ks = (kit + S - 1) / S;
        dim3 g(N / 64, 16, S);
        if (fast) gemm_mfma<0,true ><<<g, 256, 0, stream>>>(in, W, bia, outp, N, K, lda, N, N, kit, ks, Pbuf);
        else      gemm_mfma<0,false><<<g, 256, 0, stream>>>(in, W, bia, outp, N, K, lda, N, N, kit, ks, Pbuf);
        if (S > 1) {
            dim3 ge((N / 4) / 64, B_N / 4);
            epi_pack_kernel<<<ge, 256, 0, stream>>>(Pbuf, bia, outp, N / 4, S);
        }
    };

    runL(h0p, W1, b1, h1p, 1536, H0_W, H0_W, S1, false);
    runL(h1p, W2, b2, h2p, 1024, 1536, 1536, S2, true);
    runL(h2p, W3, b3, h3p,  512, 1024, 1024, S3, true);
    runL(h3p, W4, b4, h4p,  256,  512,  512, S4, true);

    final_kernel<<<B_N / 4, 256, 0, stream>>>(h4p, W5, b5, out);
}

// Round 5
// 128.671 us; speedup vs baseline: 2.1934x; 2.1934x over previous
//
#include <hip/hip_runtime.h>
#include <hip/hip_bf16.h>

#define B_N     1024
#define IN_DIM  165
#define EMB_D   150
#define FEAT    315
#define H0_W    325
#define H0_S    352     // padded row stride of h0 (u32), 11*32
#define MB_OUT  10
#define MB_INT  50
#define MROW    64

typedef __attribute__((ext_vector_type(8))) short short8;
typedef __attribute__((ext_vector_type(4))) float f32x4;

__device__ __forceinline__ ushort f2bf(float f) {
    uint u = __float_as_uint(f);
    return (ushort)((u + 0x7fffu + ((u >> 16) & 1u)) >> 16);
}
__device__ __forceinline__ uint pack_split(float v) {
    ushort h = f2bf(v);
    float hf = __uint_as_float((uint)h << 16);
    ushort l = f2bf(v - hf);
    return (uint)h | ((uint)l << 16);
}
__device__ __forceinline__ float unpack_split(uint u) {
    return __uint_as_float(u << 16) + __uint_as_float(u & 0xffff0000u);
}

// ---------------- build x = concat(ts, emb[cond]) packed, zero K-pad -----------
__global__ __launch_bounds__(320) void build_x_kernel(
    const float* __restrict__ ts, const int* __restrict__ cond,
    const float* __restrict__ emb, uint* __restrict__ h0p)
{
    int b = blockIdx.x, t = threadIdx.x;
    if (t < 37) h0p[b * H0_S + FEAT + t] = 0u;   // zero cols [315,352)
    float v;
    if (t < IN_DIM)      v = ts[b * IN_DIM + t];
    else if (t < FEAT)   v = emb[cond[b] * EMB_D + (t - IN_DIM)];
    else return;
    h0p[b * H0_S + t] = pack_split(v);
}

// ---------------- MFMA bf16-split GEMM with optional K-split -------------------
// A: packed u32 [1024 x >=kIter*32] lda (16B-aligned rows, zero-padded K)
// B: fp32 [K x N] ldb
// MODE 1: vector A loads, guarded B (k < K, col < N). MODE 2: all unguarded.
// gridDim.z>1: fp32 partials to Pout + z*B_N*N. Else EPI0: pack+lrelu+bias;
// EPI1: M2-permuted fp32 store.
template<int EPI, int MODE>
__global__ __launch_bounds__(256) void gemm_mfma(
    const uint*  __restrict__ Ap, const float* __restrict__ Bw,
    const float* __restrict__ bias, void* __restrict__ Cout,
    int N, int K, int lda, int ldb, int ldc,
    int kIterTotal, int Ks, float* __restrict__ Pout)
{
    __shared__ ushort Ah[64 * 32], Al[64 * 32], Bh[64 * 32], Bl[64 * 32];

    const int t    = threadIdx.x;
    const int bm   = blockIdx.y << 6;
    const int bn   = blockIdx.x << 6;
    const int wid  = t >> 6, lane = t & 63;
    const int wm   = (wid >> 1) << 5, wn = (wid & 1) << 5;
    const int lm   = lane & 15, lc = lane >> 4;

    const int ar  = t >> 2, ac = t & 3;
    const int bn2 = t & 63, bk = t >> 6;

    const int z   = blockIdx.z;
    const int it0 = z * Ks;
    const int nIt = min(Ks, kIterTotal - it0);

    const int aw = ar  * 32 + ((ac ^ (ar  & 3)) << 3);
    const int bw = bn2 * 32 + ((bk ^ (bn2 & 3)) << 3);
    const int sw = (lc ^ (lm & 3)) << 3;
    const int a0 = (wm + lm)      * 32 + sw;
    const int a1 = (wm + 16 + lm) * 32 + sw;
    const int b0 = (wn + lm)      * 32 + sw;
    const int b1 = (wn + 16 + lm) * 32 + sw;

    uint  curA[8], nxtA[8];
    float curB[8], nxtB[8];

    auto loadA = [&](int k0, uint* dst) {
        const uint* p = Ap + (bm + ar) * lda + k0 + (ac << 3);
        uint4 v0 = *(const uint4*)p;
        uint4 v1 = *(const uint4*)(p + 4);
        dst[0] = v0.x; dst[1] = v0.y; dst[2] = v0.z; dst[3] = v0.w;
        dst[4] = v1.x; dst[5] = v1.y; dst[6] = v1.z; dst[7] = v1.w;
    };
    auto loadB = [&](int k0, float* dst) {
        int kb = k0 + (bk << 3);
        const float* p = Bw + kb * ldb + bn + bn2;
        if (MODE == 2) {
            #pragma unroll
            for (int j = 0; j < 8; ++j) dst[j] = p[j * ldb];
        } else {
            bool cok = (bn + bn2) < N;
            #pragma unroll
            for (int j = 0; j < 8; ++j)
                dst[j] = (cok && (kb + j) < K) ? p[j * ldb] : 0.f;
        }
    };

    f32x4 acc[2][2] = {};

    loadA(it0 << 5, curA);
    loadB(it0 << 5, curB);

    for (int it = 0; it < nIt; ++it) {
        short8 vah, val, vbh, vbl;
        #pragma unroll
        for (int j = 0; j < 8; ++j) {
            vah[j] = (short)(curA[j] & 0xffffu);
            val[j] = (short)(curA[j] >> 16);
            float v = curB[j];
            ushort h = f2bf(v);
            float hf = __uint_as_float((uint)h << 16);
            vbh[j] = (short)h;
            vbl[j] = (short)f2bf(v - hf);
        }
        __syncthreads();
        *(short8*)&Ah[aw] = vah;
        *(short8*)&Al[aw] = val;
        *(short8*)&Bh[bw] = vbh;
        *(short8*)&Bl[bw] = vbl;
        __syncthreads();

        if (it + 1 < nIt) {
            loadA((it0 + it + 1) << 5, nxtA);
            loadB((it0 + it + 1) << 5, nxtB);
        }

        short8 fah0 = *(const short8*)&Ah[a0];
        short8 fah1 = *(const short8*)&Ah[a1];
        short8 fal0 = *(const short8*)&Al[a0];
        short8 fal1 = *(const short8*)&Al[a1];
        short8 fbh0 = *(const short8*)&Bh[b0];
        short8 fbh1 = *(const short8*)&Bh[b1];
        short8 fbl0 = *(const short8*)&Bl[b0];
        short8 fbl1 = *(const short8*)&Bl[b1];

        acc[0][0] = __builtin_amdgcn_mfma_f32_16x16x32_bf16(fah0, fbh0, acc[0][0], 0, 0, 0);
        acc[0][1] = __builtin_amdgcn_mfma_f32_16x16x32_bf16(fah0, fbh1, acc[0][1], 0, 0, 0);
        acc[1][0] = __builtin_amdgcn_mfma_f32_16x16x32_bf16(fah1, fbh0, acc[1][0], 0, 0, 0);
        acc[1][1] = __builtin_amdgcn_mfma_f32_16x16x32_bf16(fah1, fbh1, acc[1][1], 0, 0, 0);
        acc[0][0] = __builtin_amdgcn_mfma_f32_16x16x32_bf16(fah0, fbl0, acc[0][0], 0, 0, 0);
        acc[0][1] = __builtin_amdgcn_mfma_f32_16x16x32_bf16(fah0, fbl1, acc[0][1], 0, 0, 0);
        acc[1][0] = __builtin_amdgcn_mfma_f32_16x16x32_bf16(fah1, fbl0, acc[1][0], 0, 0, 0);
        acc[1][1] = __builtin_amdgcn_mfma_f32_16x16x32_bf16(fah1, fbl1, acc[1][1], 0, 0, 0);
        acc[0][0] = __builtin_amdgcn_mfma_f32_16x16x32_bf16(fal0, fbh0, acc[0][0], 0, 0, 0);
        acc[0][1] = __builtin_amdgcn_mfma_f32_16x16x32_bf16(fal0, fbh1, acc[0][1], 0, 0, 0);
        acc[1][0] = __builtin_amdgcn_mfma_f32_16x16x32_bf16(fal1, fbh0, acc[1][0], 0, 0, 0);
        acc[1][1] = __builtin_amdgcn_mfma_f32_16x16x32_bf16(fal1, fbh1, acc[1][1], 0, 0, 0);

        #pragma unroll
        for (int j = 0; j < 8; ++j) { curA[j] = nxtA[j]; curB[j] = nxtB[j]; }
    }

    if (gridDim.z > 1) {
        float* P = Pout + (size_t)z * B_N * N;
        #pragma unroll
        for (int mi = 0; mi < 2; ++mi)
        #pragma unroll
        for (int ni = 0; ni < 2; ++ni)
        #pragma unroll
        for (int r = 0; r < 4; ++r) {
            int row = bm + wm + mi * 16 + lc * 4 + r;
            int col = bn + wn + ni * 16 + lm;
            if (col < N) P[row * N + col] = acc[mi][ni][r];
        }
        return;
    }

    #pragma unroll
    for (int mi = 0; mi < 2; ++mi)
    #pragma unroll
    for (int ni = 0; ni < 2; ++ni)
    #pragma unroll
    for (int r = 0; r < 4; ++r) {
        int row = bm + wm + mi * 16 + lc * 4 + r;
        int col = bn + wn + ni * 16 + lm;
        float v = acc[mi][ni][r];
        if (EPI == 0) {
            v += bias[col];
            v = (v > 0.f) ? v : 0.2f * v;
            ((uint*)Cout)[row * ldc + col] = pack_split(v);
        } else {
            if (col < N) {
                int o = col / MB_INT, kk = col - o * MB_INT;
                ((float*)Cout)[(o * B_N + row) * MROW + kk] = v;
            }
        }
    }
}

// ---------------- split-K epilogues -------------------------------------------
__global__ __launch_bounds__(256) void epi_pack_kernel(
    const float* __restrict__ P, const float* __restrict__ bias,
    uint* __restrict__ outp, int n4, int S)
{
    const int c4 = blockIdx.x * 64 + (threadIdx.x & 63);
    const int r  = blockIdx.y * 4 + (threadIdx.x >> 6);
    const int idx = r * n4 + c4;
    const float4* P4 = (const float4*)P;
    float4 v = P4[idx];
    for (int s = 1; s < S; ++s) {
        float4 w = P4[(size_t)s * B_N * n4 + idx];
        v.x += w.x; v.y += w.y; v.z += w.z; v.w += w.w;
    }
    float4 bb = ((const float4*)bias)[c4];
    v.x += bb.x; v.y += bb.y; v.z += bb.z; v.w += bb.w;
    v.x = (v.x > 0.f) ? v.x : 0.2f * v.x;
    v.y = (v.y > 0.f) ? v.y : 0.2f * v.y;
    v.z = (v.z > 0.f) ? v.z : 0.2f * v.z;
    v.w = (v.w > 0.f) ? v.w : 0.2f * v.w;
    uint4 o;
    o.x = pack_split(v.x); o.y = pack_split(v.y);
    o.z = pack_split(v.z); o.w = pack_split(v.w);
    ((uint4*)outp)[idx] = o;
}

__global__ __launch_bounds__(256) void epi_m2_kernel(
    const float* __restrict__ P, float* __restrict__ M2, int S)
{
    int i = blockIdx.x * 256 + threadIdx.x;   // < 1024*500
    if (i >= B_N * 500) return;
    int r = i / 500, c = i - r * 500;
    float v = P[i];
    for (int s = 1; s < S; ++s) v += P[(size_t)s * B_N * 500 + i];
    int o = c / MB_INT, k = c - o * MB_INT;
    M2[(o * B_N + r) * MROW + k] = v;
}

// ---------------- pairwise L1 + exp with exact underflow early-exit ------------
// R2 structure (LDS-broadcast B chunk). Exact shortcut: L1 accumulates
// monotonically; if the 16-elem prefix already exceeds 110, exp(-d) is exactly
// +0.0f in fp32 (2^-158 < min denormal), so the step contributes nothing.
// __all() makes the skip wave-uniform; any lane below threshold -> exact full
// path for the whole wave (self term exp(0)=1 handled there automatically).
__global__ __launch_bounds__(256) void pairwise_kernel(
    const float* __restrict__ M2, float* __restrict__ part)
{
    __shared__ float Ls[64][64];
    const int grp = blockIdx.x, o = blockIdx.y, ch = blockIdx.z;
    const int t = threadIdx.x, wid = t >> 6, lane = t & 63;

    {
        const float4* src = (const float4*)(M2 + (o * B_N + ch * 64) * MROW);
        #pragma unroll
        for (int s = 0; s < 4; ++s)
            ((float4*)Ls)[t + s * 256] = src[t + s * 256];
    }
    __syncthreads();

    const int At = grp * 4 + wid;
    const int b  = At * 64 + lane;

    float m[50];
    const float* Arow = M2 + (o * B_N + b) * MROW;
    #pragma unroll
    for (int j = 0; j < 12; ++j) {
        float4 v = ((const float4*)Arow)[j];
        m[j*4+0] = v.x; m[j*4+1] = v.y; m[j*4+2] = v.z; m[j*4+3] = v.w;
    }
    { float2 v = *(const float2*)(Arow + 48); m[48] = v.x; m[49] = v.y; }

    float acc = 0.f;
    for (int b2 = 0; b2 < 64; ++b2) {
        const float4* q = (const float4*)&Ls[b2][0];
        float t0 = 0.f, t1 = 0.f, t2 = 0.f, t3 = 0.f;
        #pragma unroll
        for (int j4 = 0; j4 < 4; ++j4) {
            float4 v = q[j4];
            t0 += fabsf(m[j4*4+0] - v.x);
            t1 += fabsf(m[j4*4+1] - v.y);
            t2 += fabsf(m[j4*4+2] - v.z);
            t3 += fabsf(m[j4*4+3] - v.w);
        }
        float d16 = (t0 + t1) + (t2 + t3);
        if (__all(d16 > 110.f)) continue;      // exp underflows: exact +0.0f

        #pragma unroll
        for (int j4 = 4; j4 < 12; ++j4) {
            float4 v = q[j4];
            t0 += fabsf(m[j4*4+0] - v.x);
            t1 += fabsf(m[j4*4+1] - v.y);
            t2 += fabsf(m[j4*4+2] - v.z);
            t3 += fabsf(m[j4*4+3] - v.w);
        }
        {
            float4 v = q[12];
            t0 += fabsf(m[48] - v.x);
            t1 += fabsf(m[49] - v.y);
        }
        acc += __expf(-((t0 + t1) + (t2 + t3)));
    }
    part[(ch * MB_OUT + o) * B_N + b] = acc;
}

// ---------------- reduce 16 partials into h0p[:, 315:325] ----------------------
__global__ __launch_bounds__(256) void mb_reduce_kernel(
    const float* __restrict__ part, uint* __restrict__ h0p)
{
    int i = blockIdx.x * 256 + threadIdx.x;
    if (i < MB_OUT * B_N) {
        int o = i / B_N, b = i - o * B_N;
        float s = 0.f;
        #pragma unroll
        for (int ch = 0; ch < 16; ++ch)
            s += part[(ch * MB_OUT + o) * B_N + b];
        h0p[b * H0_S + FEAT + o] = pack_split(s);
    }
}

// ---------------- final layer: sigmoid(h4 @ W5 + b5) ---------------------------
__global__ __launch_bounds__(256) void final_kernel(
    const uint* __restrict__ h4p, const float* __restrict__ W5,
    const float* __restrict__ b5, float* __restrict__ out)
{
    const int wave = threadIdx.x >> 6;
    const int lane = threadIdx.x & 63;
    const int row  = blockIdx.x * 4 + wave;

    const uint4  h = ((const uint4*)(h4p + row * 256))[lane];
    const float4 w = ((const float4*)W5)[lane];
    float s = unpack_split(h.x) * w.x + unpack_split(h.y) * w.y
            + unpack_split(h.z) * w.z + unpack_split(h.w) * w.w;
    #pragma unroll
    for (int off = 32; off > 0; off >>= 1)
        s += __shfl_xor(s, off);
    if (lane == 0) {
        float z = s + b5[0];
        out[row] = 1.f / (1.f + __expf(-z));
    }
}

// ---------------- launch -------------------------------------------------------
extern "C" void kernel_launch(void* const* d_in, const int* in_sizes, int n_in,
                              void* d_out, int out_size, void* d_ws, size_t ws_size,
                              hipStream_t stream)
{
    const float* ts   = (const float*)d_in[0];
    const int*   cond = (const int*)  d_in[1];
    const float* emb  = (const float*)d_in[2];
    const float* T    = (const float*)d_in[3];
    const float* W1   = (const float*)d_in[4];
    const float* b1   = (const float*)d_in[5];
    const float* W2   = (const float*)d_in[6];
    const float* b2   = (const float*)d_in[7];
    const float* W3   = (const float*)d_in[8];
    const float* b3   = (const float*)d_in[9];
    const float* W4   = (const float*)d_in[10];
    const float* b4   = (const float*)d_in[11];
    const float* W5   = (const float*)d_in[12];
    const float* b5   = (const float*)d_in[13];
    float* out = (float*)d_out;

    // workspace (4-byte units)
    uint*  h0p  = (uint*)d_ws;             // 1024*352   = 360448
    float* M2   = (float*)(h0p + 360448);  // 10*1024*64 = 655360
    float* part = M2 + 655360;             // 16*10*1024 = 163840
    uint*  h1p  = (uint*)(part + 163840);  // 1572864
    uint*  h2p  = h1p + 1572864;           // 1048576
    uint*  h3p  = (uint*)M2;               // alias (524288 <= 655360)
    uint*  h4p  = h1p;                     // alias
    const size_t baseU = 360448 + 655360 + 163840 + 1572864 + 1048576; // 3801088
    size_t capU = (ws_size / 4 > baseU) ? ws_size / 4 - baseU : 0;
    float* Pbuf = (float*)((uint*)d_ws + baseU);

    auto fits = [&](int s, int N) { return (size_t)s * B_N * N <= capU; };
    const int ST = fits(2, 500)  ? 2 : 1;
    const int S1 = fits(2, 1536) ? 2 : 1;
    const int S2 = fits(3, 1024) ? 3 : (fits(2, 1024) ? 2 : 1);
    const int S3 = fits(4, 512)  ? 4 : (fits(2, 512)  ? 2 : 1);
    const int S4 = fits(4, 256)  ? 4 : (fits(2, 256)  ? 2 : 1);

    build_x_kernel<<<B_N, 320, 0, stream>>>(ts, cond, emb, h0p);

    // M = x @ T (K=315, N=500), vector-A (zero-padded), guarded B
    {
        int kit = 10, ks = (kit + ST - 1) / ST;
        dim3 g(8, 16, ST);
        gemm_mfma<1,1><<<g, 256, 0, stream>>>(h0p, T, nullptr, M2,
                                              500, FEAT, H0_S, 500, 0, kit, ks, Pbuf);
        if (ST > 1)
            epi_m2_kernel<<<(B_N * 500 + 255) / 256, 256, 0, stream>>>(Pbuf, M2, ST);
    }

    { dim3 g(4, MB_OUT, 16); pairwise_kernel<<<g, 256, 0, stream>>>(M2, part); }
    mb_reduce_kernel<<<(MB_OUT * B_N + 255) / 256, 256, 0, stream>>>(part, h0p);

    // W1: K=325, kIter=11 (A zero-padded to 352), guarded B
    {
        int kit = 11, ks = (kit + S1 - 1) / S1;
        dim3 g(24, 16, S1);
        gemm_mfma<0,1><<<g, 256, 0, stream>>>(h0p, W1, b1, h1p,
                                              1536, H0_W, H0_S, 1536, 1536, kit, ks, Pbuf);
        if (S1 > 1) {
            dim3 ge(6, 256);
            epi_pack_kernel<<<ge, 256, 0, stream>>>(Pbuf, b1, h1p, 384, S1);
        }
    };

    auto runL = [&](const uint* in, const float* W, const float* bia, uint* outp,
                    int N, int K, int lda, int S) {
        int kit = K >> 5, ks = (kit + S - 1) / S;
        dim3 g(N / 64, 16, S);
        gemm_mfma<0,2><<<g, 256, 0, stream>>>(in, W, bia, outp, N, K, lda, N, N, kit, ks, Pbuf);
        if (S > 1) {
            dim3 ge((N / 4) / 64, B_N / 4);
            epi_pack_kernel<<<ge, 256, 0, stream>>>(Pbuf, bia, outp, N / 4, S);
        }
    };

    runL(h1p, W2, b2, h2p, 1024, 1536, 1536, S2);
    runL(h2p, W3, b3, h3p,  512, 1024, 1024, S3);
    runL(h3p, W4, b4, h4p,  256,  512,  512, S4);

    final_kernel<<<B_N / 4, 256, 0, stream>>>(h4p, W5, b5, out);
}

// Round 6
// 125.958 us; speedup vs baseline: 2.2406x; 1.0215x over previous
//
#include <hip/hip_runtime.h>
#include <hip/hip_bf16.h>

#define B_N     1024
#define IN_DIM  165
#define EMB_D   150
#define FEAT    315
#define H0_W    325
#define H0_S    352     // padded row stride of h0 (u32), 11*32
#define MB_OUT  10
#define MB_INT  50
#define MROW    64

typedef __attribute__((ext_vector_type(8))) short short8;
typedef __attribute__((ext_vector_type(4))) float f32x4;

__device__ __forceinline__ ushort f2bf(float f) {
    uint u = __float_as_uint(f);
    return (ushort)((u + 0x7fffu + ((u >> 16) & 1u)) >> 16);
}
__device__ __forceinline__ uint pack_split(float v) {
    ushort h = f2bf(v);
    float hf = __uint_as_float((uint)h << 16);
    ushort l = f2bf(v - hf);
    return (uint)h | ((uint)l << 16);
}
__device__ __forceinline__ float unpack_split(uint u) {
    return __uint_as_float(u << 16) + __uint_as_float(u & 0xffff0000u);
}

// ---------------- build x = concat(ts, emb[cond]) packed, zero K-pad -----------
__global__ __launch_bounds__(320) void build_x_kernel(
    const float* __restrict__ ts, const int* __restrict__ cond,
    const float* __restrict__ emb, uint* __restrict__ h0p)
{
    int b = blockIdx.x, t = threadIdx.x;
    if (t < 37) h0p[b * H0_S + FEAT + t] = 0u;   // zero cols [315,352)
    float v;
    if (t < IN_DIM)      v = ts[b * IN_DIM + t];
    else if (t < FEAT)   v = emb[cond[b] * EMB_D + (t - IN_DIM)];
    else return;
    h0p[b * H0_S + t] = pack_split(v);
}

// ---------------- weight pre-pack: fp32 [K][N] -> split-bf16 u32 [Kpad][Npad] --
__global__ __launch_bounds__(256) void pack_w_kernel(
    const float* __restrict__ W, uint* __restrict__ Wp,
    int K, int N, int Npad, int total)
{
    int i = blockIdx.x * 256 + threadIdx.x;
    if (i >= total) return;
    int k = i / Npad, n = i - k * Npad;
    float v = (k < K && n < N) ? W[k * N + n] : 0.f;
    Wp[i] = pack_split(v);
}

// ---------------- MFMA bf16-split GEMM with optional K-split -------------------
// A: packed u32 [1024 x >=kIter*32] lda (16B-aligned rows, zero-padded K)
// PACKED=1: B = packed u32 [Kpad][ldb], unguarded. PACKED=0: B = fp32, guarded.
// gridDim.z>1: fp32 partials to Pout + z*B_N*N. Else EPI0: pack+lrelu+bias;
// EPI1: M2-permuted fp32 store (col<N guard).
template<int EPI, int PACKED>
__global__ __launch_bounds__(256) void gemm_mfma(
    const uint*  __restrict__ Ap, const void* __restrict__ Bw,
    const float* __restrict__ bias, void* __restrict__ Cout,
    int N, int K, int lda, int ldb, int ldc,
    int kIterTotal, int Ks, float* __restrict__ Pout)
{
    __shared__ ushort Ah[64 * 32], Al[64 * 32], Bh[64 * 32], Bl[64 * 32];

    const int t    = threadIdx.x;
    const int bm   = blockIdx.y << 6;
    const int bn   = blockIdx.x << 6;
    const int wid  = t >> 6, lane = t & 63;
    const int wm   = (wid >> 1) << 5, wn = (wid & 1) << 5;
    const int lm   = lane & 15, lc = lane >> 4;

    const int ar  = t >> 2, ac = t & 3;
    const int bn2 = t & 63, bk = t >> 6;

    const int z   = blockIdx.z;
    const int it0 = z * Ks;
    const int nIt = min(Ks, kIterTotal - it0);

    const int aw = ar  * 32 + ((ac ^ (ar  & 3)) << 3);
    const int bw = bn2 * 32 + ((bk ^ (bn2 & 3)) << 3);
    const int sw = (lc ^ (lm & 3)) << 3;
    const int a0 = (wm + lm)      * 32 + sw;
    const int a1 = (wm + 16 + lm) * 32 + sw;
    const int b0 = (wn + lm)      * 32 + sw;
    const int b1 = (wn + 16 + lm) * 32 + sw;

    uint curA[8], nxtA[8], curB[8], nxtB[8];

    auto loadA = [&](int k0, uint* dst) {
        const uint* p = Ap + (bm + ar) * lda + k0 + (ac << 3);
        uint4 v0 = *(const uint4*)p;
        uint4 v1 = *(const uint4*)(p + 4);
        dst[0] = v0.x; dst[1] = v0.y; dst[2] = v0.z; dst[3] = v0.w;
        dst[4] = v1.x; dst[5] = v1.y; dst[6] = v1.z; dst[7] = v1.w;
    };
    auto loadB = [&](int k0, uint* dst) {
        int kb = k0 + (bk << 3);
        if (PACKED) {
            const uint* p = (const uint*)Bw + kb * ldb + bn + bn2;
            #pragma unroll
            for (int j = 0; j < 8; ++j) dst[j] = p[j * ldb];
        } else {
            const float* p = (const float*)Bw + kb * ldb + bn + bn2;
            bool cok = (bn + bn2) < N;
            #pragma unroll
            for (int j = 0; j < 8; ++j)
                dst[j] = __float_as_uint((cok && (kb + j) < K) ? p[j * ldb] : 0.f);
        }
    };

    f32x4 acc[2][2] = {};

    loadA(it0 << 5, curA);
    loadB(it0 << 5, curB);

    for (int it = 0; it < nIt; ++it) {
        short8 vah, val, vbh, vbl;
        #pragma unroll
        for (int j = 0; j < 8; ++j) {
            uint ua = curA[j];
            vah[j] = (short)(ua & 0xffffu);
            val[j] = (short)(ua >> 16);
            if (PACKED) {
                uint ub = curB[j];
                vbh[j] = (short)(ub & 0xffffu);
                vbl[j] = (short)(ub >> 16);
            } else {
                float v = __uint_as_float(curB[j]);
                ushort h = f2bf(v);
                float hf = __uint_as_float((uint)h << 16);
                vbh[j] = (short)h;
                vbl[j] = (short)f2bf(v - hf);
            }
        }
        __syncthreads();
        *(short8*)&Ah[aw] = vah;
        *(short8*)&Al[aw] = val;
        *(short8*)&Bh[bw] = vbh;
        *(short8*)&Bl[bw] = vbl;
        __syncthreads();

        if (it + 1 < nIt) {
            loadA((it0 + it + 1) << 5, nxtA);
            loadB((it0 + it + 1) << 5, nxtB);
        }

        short8 fah0 = *(const short8*)&Ah[a0];
        short8 fah1 = *(const short8*)&Ah[a1];
        short8 fal0 = *(const short8*)&Al[a0];
        short8 fal1 = *(const short8*)&Al[a1];
        short8 fbh0 = *(const short8*)&Bh[b0];
        short8 fbh1 = *(const short8*)&Bh[b1];
        short8 fbl0 = *(const short8*)&Bl[b0];
        short8 fbl1 = *(const short8*)&Bl[b1];

        acc[0][0] = __builtin_amdgcn_mfma_f32_16x16x32_bf16(fah0, fbh0, acc[0][0], 0, 0, 0);
        acc[0][1] = __builtin_amdgcn_mfma_f32_16x16x32_bf16(fah0, fbh1, acc[0][1], 0, 0, 0);
        acc[1][0] = __builtin_amdgcn_mfma_f32_16x16x32_bf16(fah1, fbh0, acc[1][0], 0, 0, 0);
        acc[1][1] = __builtin_amdgcn_mfma_f32_16x16x32_bf16(fah1, fbh1, acc[1][1], 0, 0, 0);
        acc[0][0] = __builtin_amdgcn_mfma_f32_16x16x32_bf16(fah0, fbl0, acc[0][0], 0, 0, 0);
        acc[0][1] = __builtin_amdgcn_mfma_f32_16x16x32_bf16(fah0, fbl1, acc[0][1], 0, 0, 0);
        acc[1][0] = __builtin_amdgcn_mfma_f32_16x16x32_bf16(fah1, fbl0, acc[1][0], 0, 0, 0);
        acc[1][1] = __builtin_amdgcn_mfma_f32_16x16x32_bf16(fah1, fbl1, acc[1][1], 0, 0, 0);
        acc[0][0] = __builtin_amdgcn_mfma_f32_16x16x32_bf16(fal0, fbh0, acc[0][0], 0, 0, 0);
        acc[0][1] = __builtin_amdgcn_mfma_f32_16x16x32_bf16(fal0, fbh1, acc[0][1], 0, 0, 0);
        acc[1][0] = __builtin_amdgcn_mfma_f32_16x16x32_bf16(fal1, fbh0, acc[1][0], 0, 0, 0);
        acc[1][1] = __builtin_amdgcn_mfma_f32_16x16x32_bf16(fal1, fbh1, acc[1][1], 0, 0, 0);

        #pragma unroll
        for (int j = 0; j < 8; ++j) { curA[j] = nxtA[j]; curB[j] = nxtB[j]; }
    }

    if (gridDim.z > 1) {
        float* P = Pout + (size_t)z * B_N * N;
        #pragma unroll
        for (int mi = 0; mi < 2; ++mi)
        #pragma unroll
        for (int ni = 0; ni < 2; ++ni)
        #pragma unroll
        for (int r = 0; r < 4; ++r) {
            int row = bm + wm + mi * 16 + lc * 4 + r;
            int col = bn + wn + ni * 16 + lm;
            if (col < N) P[row * N + col] = acc[mi][ni][r];
        }
        return;
    }

    #pragma unroll
    for (int mi = 0; mi < 2; ++mi)
    #pragma unroll
    for (int ni = 0; ni < 2; ++ni)
    #pragma unroll
    for (int r = 0; r < 4; ++r) {
        int row = bm + wm + mi * 16 + lc * 4 + r;
        int col = bn + wn + ni * 16 + lm;
        float v = acc[mi][ni][r];
        if (EPI == 0) {
            v += bias[col];
            v = (v > 0.f) ? v : 0.2f * v;
            ((uint*)Cout)[row * ldc + col] = pack_split(v);
        } else {
            if (col < N) {
                int o = col / MB_INT, kk = col - o * MB_INT;
                ((float*)Cout)[(o * B_N + row) * MROW + kk] = v;
            }
        }
    }
}

// ---------------- split-K epilogues -------------------------------------------
__global__ __launch_bounds__(256) void epi_pack_kernel(
    const float* __restrict__ P, const float* __restrict__ bias,
    uint* __restrict__ outp, int n4, int S)
{
    const int c4 = blockIdx.x * 64 + (threadIdx.x & 63);
    const int r  = blockIdx.y * 4 + (threadIdx.x >> 6);
    const int idx = r * n4 + c4;
    const float4* P4 = (const float4*)P;
    float4 v = P4[idx];
    for (int s = 1; s < S; ++s) {
        float4 w = P4[(size_t)s * B_N * n4 + idx];
        v.x += w.x; v.y += w.y; v.z += w.z; v.w += w.w;
    }
    float4 bb = ((const float4*)bias)[c4];
    v.x += bb.x; v.y += bb.y; v.z += bb.z; v.w += bb.w;
    v.x = (v.x > 0.f) ? v.x : 0.2f * v.x;
    v.y = (v.y > 0.f) ? v.y : 0.2f * v.y;
    v.z = (v.z > 0.f) ? v.z : 0.2f * v.z;
    v.w = (v.w > 0.f) ? v.w : 0.2f * v.w;
    uint4 o;
    o.x = pack_split(v.x); o.y = pack_split(v.y);
    o.z = pack_split(v.z); o.w = pack_split(v.w);
    ((uint4*)outp)[idx] = o;
}

__global__ __launch_bounds__(256) void epi_m2_kernel(
    const float* __restrict__ P, float* __restrict__ M2, int S)
{
    int i = blockIdx.x * 256 + threadIdx.x;   // < 1024*500
    if (i >= B_N * 500) return;
    int r = i / 500, c = i - r * 500;
    float v = P[i];
    for (int s = 1; s < S; ++s) v += P[(size_t)s * B_N * 500 + i];
    int o = c / MB_INT, k = c - o * MB_INT;
    M2[(o * B_N + r) * MROW + k] = v;
}

// ---------------- pairwise L1 + exp: underflow early-exit, unroll-2 ------------
// grid (4, 10, 32): 32 chunks of 32 B-rows (8KB LDS), 1280 blocks for latency
// hiding. Own row pinned in 13 named float4 registers. Steps unrolled x2 with
// combined wave-uniform skip: if min(d0,d1) prefix > 110 on every lane, both
// exps are exactly +0.0f (2^-158 underflows). Exact either way.
#define ABS4(dacc, Avec, qptr, idx) { \
    float4 v_ = ((const float4*)(qptr))[idx]; \
    dacc.x += fabsf(Avec.x - v_.x); dacc.y += fabsf(Avec.y - v_.y); \
    dacc.z += fabsf(Avec.z - v_.z); dacc.w += fabsf(Avec.w - v_.w); }

__global__ __launch_bounds__(256) void pairwise_kernel(
    const float* __restrict__ M2, float* __restrict__ part)
{
    __shared__ float Ls[32][64];
    const int grp = blockIdx.x, o = blockIdx.y, ch = blockIdx.z;
    const int t = threadIdx.x, wid = t >> 6, lane = t & 63;

    {
        const float4* src = (const float4*)(M2 + (o * B_N + ch * 32) * MROW);
        ((float4*)Ls)[t]       = src[t];
        ((float4*)Ls)[t + 256] = src[t + 256];
    }
    __syncthreads();

    const int b = (grp * 4 + wid) * 64 + lane;
    const float4* Ar = (const float4*)(M2 + (o * B_N + b) * MROW);
    float4 A0 = Ar[0], A1 = Ar[1], A2 = Ar[2],  A3 = Ar[3];
    float4 A4 = Ar[4], A5 = Ar[5], A6 = Ar[6],  A7 = Ar[7];
    float4 A8 = Ar[8], A9 = Ar[9], A10 = Ar[10], A11 = Ar[11];
    float4 A12; { float2 v = *(const float2*)((const float*)Ar + 48); A12.x = v.x; A12.y = v.y; }

    float acc = 0.f;
    #pragma unroll 4
    for (int b2 = 0; b2 < 32; b2 += 2) {
        const float* q0 = &Ls[b2][0];
        const float* q1 = &Ls[b2 + 1][0];
        float4 dA = {0.f,0.f,0.f,0.f}, dB = {0.f,0.f,0.f,0.f};
        ABS4(dA, A0, q0, 0) ABS4(dA, A1, q0, 1) ABS4(dA, A2, q0, 2) ABS4(dA, A3, q0, 3)
        ABS4(dB, A0, q1, 0) ABS4(dB, A1, q1, 1) ABS4(dB, A2, q1, 2) ABS4(dB, A3, q1, 3)
        float d0 = (dA.x + dA.y) + (dA.z + dA.w);
        float d1 = (dB.x + dB.y) + (dB.z + dB.w);
        if (__all(fminf(d0, d1) > 110.f)) continue;   // both exactly 0

        ABS4(dA, A4, q0, 4) ABS4(dA, A5, q0, 5) ABS4(dA, A6,  q0, 6)  ABS4(dA, A7,  q0, 7)
        ABS4(dA, A8, q0, 8) ABS4(dA, A9, q0, 9) ABS4(dA, A10, q0, 10) ABS4(dA, A11, q0, 11)
        { float4 v_ = ((const float4*)q0)[12];
          dA.x += fabsf(A12.x - v_.x); dA.y += fabsf(A12.y - v_.y); }
        ABS4(dB, A4, q1, 4) ABS4(dB, A5, q1, 5) ABS4(dB, A6,  q1, 6)  ABS4(dB, A7,  q1, 7)
        ABS4(dB, A8, q1, 8) ABS4(dB, A9, q1, 9) ABS4(dB, A10, q1, 10) ABS4(dB, A11, q1, 11)
        { float4 v_ = ((const float4*)q1)[12];
          dB.x += fabsf(A12.x - v_.x); dB.y += fabsf(A12.y - v_.y); }
        d0 = (dA.x + dA.y) + (dA.z + dA.w);
        d1 = (dB.x + dB.y) + (dB.z + dB.w);
        acc += __expf(-d0) + __expf(-d1);
    }
    part[(ch * MB_OUT + o) * B_N + b] = acc;
}

// ---------------- reduce 32 partials into h0p[:, 315:325] ----------------------
__global__ __launch_bounds__(256) void mb_reduce_kernel(
    const float* __restrict__ part, uint* __restrict__ h0p)
{
    int i = blockIdx.x * 256 + threadIdx.x;
    if (i < MB_OUT * B_N) {
        int o = i / B_N, b = i - o * B_N;
        float s = 0.f;
        #pragma unroll
        for (int ch = 0; ch < 32; ++ch)
            s += part[(ch * MB_OUT + o) * B_N + b];
        h0p[b * H0_S + FEAT + o] = pack_split(s);
    }
}

// ---------------- final layer: sigmoid(h4 @ W5 + b5) ---------------------------
__global__ __launch_bounds__(256) void final_kernel(
    const uint* __restrict__ h4p, const float* __restrict__ W5,
    const float* __restrict__ b5, float* __restrict__ out)
{
    const int wave = threadIdx.x >> 6;
    const int lane = threadIdx.x & 63;
    const int row  = blockIdx.x * 4 + wave;

    const uint4  h = ((const uint4*)(h4p + row * 256))[lane];
    const float4 w = ((const float4*)W5)[lane];
    float s = unpack_split(h.x) * w.x + unpack_split(h.y) * w.y
            + unpack_split(h.z) * w.z + unpack_split(h.w) * w.w;
    #pragma unroll
    for (int off = 32; off > 0; off >>= 1)
        s += __shfl_xor(s, off);
    if (lane == 0) {
        float z = s + b5[0];
        out[row] = 1.f / (1.f + __expf(-z));
    }
}

// ---------------- launch -------------------------------------------------------
extern "C" void kernel_launch(void* const* d_in, const int* in_sizes, int n_in,
                              void* d_out, int out_size, void* d_ws, size_t ws_size,
                              hipStream_t stream)
{
    const float* ts   = (const float*)d_in[0];
    const int*   cond = (const int*)  d_in[1];
    const float* emb  = (const float*)d_in[2];
    const float* T    = (const float*)d_in[3];
    const float* W1   = (const float*)d_in[4];
    const float* b1   = (const float*)d_in[5];
    const float* W2   = (const float*)d_in[6];
    const float* b2   = (const float*)d_in[7];
    const float* W3   = (const float*)d_in[8];
    const float* b3   = (const float*)d_in[9];
    const float* W4   = (const float*)d_in[10];
    const float* b4   = (const float*)d_in[11];
    const float* W5   = (const float*)d_in[12];
    const float* b5   = (const float*)d_in[13];
    float* out = (float*)d_out;

    // workspace (4-byte units)
    uint*  h0p  = (uint*)d_ws;             // 1024*352   = 360448
    float* M2   = (float*)(h0p + 360448);  // 10*1024*64 = 655360
    uint*  h1p  = (uint*)(M2 + 655360);    // 1572864
    uint*  h2p  = h1p + 1572864;           // 1048576
    uint*  h3p  = (uint*)M2;               // alias (524288 <= 655360)
    uint*  h4p  = h1p;                     // alias
    float* part = (float*)h1p;             // alias: 32*10*1024=327680, dead before W1
    const size_t baseU = 360448 + 655360 + 1572864 + 1048576;   // 3637248 (14.5MB)

    // packed weights (after base)
    uint* Tp  = (uint*)d_ws + baseU;       // 320*512   = 163840
    uint* W1p = Tp  + 163840;              // 352*1536  = 540672
    uint* W2p = W1p + 540672;              // 1536*1024 = 1572864
    uint* W3p = W2p + 1572864;             // 1024*512  = 524288
    uint* W4p = W3p + 524288;              // 512*256   = 131072
    const size_t packU = 163840 + 540672 + 1572864 + 524288 + 131072; // 2932736
    const bool packed = (ws_size / 4) >= (baseU + packU);

    const size_t pbase = packed ? baseU + packU : baseU;
    size_t capU = (ws_size / 4 > pbase) ? ws_size / 4 - pbase : 0;
    float* Pbuf = (float*)((uint*)d_ws + pbase);

    auto fits = [&](int s, int N) { return (size_t)s * B_N * N <= capU; };
    const int ST = fits(2, 500)  ? 2 : 1;
    const int S1 = fits(2, 1536) ? 2 : 1;
    const int S2 = fits(3, 1024) ? 3 : (fits(2, 1024) ? 2 : 1);
    const int S3 = fits(4, 512)  ? 4 : (fits(2, 512)  ? 2 : 1);
    const int S4 = fits(4, 256)  ? 4 : (fits(2, 256)  ? 2 : 1);

    if (packed) {
        pack_w_kernel<<<(163840  + 255) / 256, 256, 0, stream>>>(T,  Tp,  FEAT, 500,  512,  163840);
        pack_w_kernel<<<(540672  + 255) / 256, 256, 0, stream>>>(W1, W1p, H0_W, 1536, 1536, 540672);
        pack_w_kernel<<<(1572864 + 255) / 256, 256, 0, stream>>>(W2, W2p, 1536, 1024, 1024, 1572864);
        pack_w_kernel<<<(524288  + 255) / 256, 256, 0, stream>>>(W3, W3p, 1024, 512,  512,  524288);
        pack_w_kernel<<<(131072  + 255) / 256, 256, 0, stream>>>(W4, W4p, 512,  256,  256,  131072);
    }

    build_x_kernel<<<B_N, 320, 0, stream>>>(ts, cond, emb, h0p);

    // M = x @ T (K=315->320, N=500->512 packed)
    {
        int kit = 10, ks = (kit + ST - 1) / ST;
        dim3 g(8, 16, ST);
        if (packed)
            gemm_mfma<1,1><<<g, 256, 0, stream>>>(h0p, Tp, nullptr, M2,
                                                  500, FEAT, H0_S, 512, 0, kit, ks, Pbuf);
        else
            gemm_mfma<1,0><<<g, 256, 0, stream>>>(h0p, T, nullptr, M2,
                                                  500, FEAT, H0_S, 500, 0, kit, ks, Pbuf);
        if (ST > 1)
            epi_m2_kernel<<<(B_N * 500 + 255) / 256, 256, 0, stream>>>(Pbuf, M2, ST);
    }

    { dim3 g(4, MB_OUT, 32); pairwise_kernel<<<g, 256, 0, stream>>>(M2, part); }
    mb_reduce_kernel<<<(MB_OUT * B_N + 255) / 256, 256, 0, stream>>>(part, h0p);

    auto runL = [&](const uint* in, const float* Wf, const uint* Wp,
                    const float* bia, uint* outp, int N, int K, int lda,
                    int kit, int ldbp, int S) {
        int ks = (kit + S - 1) / S;
        dim3 g(N / 64, 16, S);
        if (packed)
            gemm_mfma<0,1><<<g, 256, 0, stream>>>(in, Wp, bia, outp, N, K, lda, ldbp, N, kit, ks, Pbuf);
        else
            gemm_mfma<0,0><<<g, 256, 0, stream>>>(in, Wf, bia, outp, N, K, lda, N,  N, kit, ks, Pbuf);
        if (S > 1) {
            dim3 ge((N / 4) / 64, B_N / 4);
            epi_pack_kernel<<<ge, 256, 0, stream>>>(Pbuf, bia, outp, N / 4, S);
        }
    };

    runL(h0p, W1, W1p, b1, h1p, 1536, H0_W, H0_S, 11, 1536, S1);
    runL(h1p, W2, W2p, b2, h2p, 1024, 1536, 1536, 48, 1024, S2);
    runL(h2p, W3, W3p, b3, h3p,  512, 1024, 1024, 32,  512, S3);
    runL(h3p, W4, W4p, b4, h4p,  256,  512,  512, 16,  256, S4);

    final_kernel<<<B_N / 4, 256, 0, stream>>>(h4p, W5, b5, out);
}

// Round 7
// 109.143 us; speedup vs baseline: 2.5858x; 1.1541x over previous
//
#include <hip/hip_runtime.h>
#include <hip/hip_bf16.h>

#define B_N     1024
#define IN_DIM  165
#define EMB_D   150
#define FEAT    315
#define H0_W    325
#define H0_S    352     // padded row stride of h0 (u32), 11*32
#define MB_OUT  10
#define MB_INT  50
#define MROW    64
#define NPROJ   12

typedef __attribute__((ext_vector_type(8))) short short8;
typedef __attribute__((ext_vector_type(4))) float f32x4;

__device__ __forceinline__ ushort f2bf(float f) {
    uint u = __float_as_uint(f);
    return (ushort)((u + 0x7fffu + ((u >> 16) & 1u)) >> 16);
}
__device__ __forceinline__ uint pack_split(float v) {
    ushort h = f2bf(v);
    float hf = __uint_as_float((uint)h << 16);
    ushort l = f2bf(v - hf);
    return (uint)h | ((uint)l << 16);
}
__device__ __forceinline__ float unpack_split(uint u) {
    return __uint_as_float(u << 16) + __uint_as_float(u & 0xffff0000u);
}

// ---------------- build x = concat(ts, emb[cond]) packed, zero K-pad -----------
__global__ __launch_bounds__(320) void build_x_kernel(
    const float* __restrict__ ts, const int* __restrict__ cond,
    const float* __restrict__ emb, uint* __restrict__ h0p)
{
    int b = blockIdx.x, t = threadIdx.x;
    if (t < 37) h0p[b * H0_S + FEAT + t] = 0u;   // zero cols [315,352)
    float v;
    if (t < IN_DIM)      v = ts[b * IN_DIM + t];
    else if (t < FEAT)   v = emb[cond[b] * EMB_D + (t - IN_DIM)];
    else return;
    h0p[b * H0_S + t] = pack_split(v);
}

// ---------------- fused weight pre-pack: all 5 weights -> split-bf16 u32 -------
// segments: T[315x500->320x512] W1[325x1536->352x1536] W2[1536x1024]
//           W3[1024x512] W4[512x256], contiguous at Wp.
__global__ __launch_bounds__(256) void pack_all_kernel(
    const float* __restrict__ T,  const float* __restrict__ W1,
    const float* __restrict__ W2, const float* __restrict__ W3,
    const float* __restrict__ W4, uint* __restrict__ Wp)
{
    int i = blockIdx.x * 256 + threadIdx.x;
    float v;
    if (i < 163840) {
        int k = i >> 9, n = i & 511;
        v = (k < FEAT && n < 500) ? T[k * 500 + n] : 0.f;
    } else if (i < 704512) {
        int j = i - 163840; int k = j / 1536, n = j - k * 1536;
        v = (k < H0_W) ? W1[k * 1536 + n] : 0.f;
    } else if (i < 2277376) {
        int j = i - 704512; v = W2[j];
    } else if (i < 2801664) {
        int j = i - 2277376; v = W3[j];
    } else if (i < 2932736) {
        int j = i - 2801664; v = W4[j];
    } else return;
    Wp[i] = pack_split(v);
}

// ---------------- MFMA bf16-split GEMM with optional K-split -------------------
template<int EPI, int PACKED>
__global__ __launch_bounds__(256) void gemm_mfma(
    const uint*  __restrict__ Ap, const void* __restrict__ Bw,
    const float* __restrict__ bias, void* __restrict__ Cout,
    int N, int K, int lda, int ldb, int ldc,
    int kIterTotal, int Ks, float* __restrict__ Pout)
{
    __shared__ ushort Ah[64 * 32], Al[64 * 32], Bh[64 * 32], Bl[64 * 32];

    const int t    = threadIdx.x;
    const int bm   = blockIdx.y << 6;
    const int bn   = blockIdx.x << 6;
    const int wid  = t >> 6, lane = t & 63;
    const int wm   = (wid >> 1) << 5, wn = (wid & 1) << 5;
    const int lm   = lane & 15, lc = lane >> 4;

    const int ar  = t >> 2, ac = t & 3;
    const int bn2 = t & 63, bk = t >> 6;

    const int z   = blockIdx.z;
    const int it0 = z * Ks;
    const int nIt = min(Ks, kIterTotal - it0);

    const int aw = ar  * 32 + ((ac ^ (ar  & 3)) << 3);
    const int bw = bn2 * 32 + ((bk ^ (bn2 & 3)) << 3);
    const int sw = (lc ^ (lm & 3)) << 3;
    const int a0 = (wm + lm)      * 32 + sw;
    const int a1 = (wm + 16 + lm) * 32 + sw;
    const int b0 = (wn + lm)      * 32 + sw;
    const int b1 = (wn + 16 + lm) * 32 + sw;

    uint curA[8], nxtA[8], curB[8], nxtB[8];

    auto loadA = [&](int k0, uint* dst) {
        const uint* p = Ap + (bm + ar) * lda + k0 + (ac << 3);
        uint4 v0 = *(const uint4*)p;
        uint4 v1 = *(const uint4*)(p + 4);
        dst[0] = v0.x; dst[1] = v0.y; dst[2] = v0.z; dst[3] = v0.w;
        dst[4] = v1.x; dst[5] = v1.y; dst[6] = v1.z; dst[7] = v1.w;
    };
    auto loadB = [&](int k0, uint* dst) {
        int kb = k0 + (bk << 3);
        if (PACKED) {
            const uint* p = (const uint*)Bw + kb * ldb + bn + bn2;
            #pragma unroll
            for (int j = 0; j < 8; ++j) dst[j] = p[j * ldb];
        } else {
            const float* p = (const float*)Bw + kb * ldb + bn + bn2;
            bool cok = (bn + bn2) < N;
            #pragma unroll
            for (int j = 0; j < 8; ++j)
                dst[j] = __float_as_uint((cok && (kb + j) < K) ? p[j * ldb] : 0.f);
        }
    };

    f32x4 acc[2][2] = {};

    loadA(it0 << 5, curA);
    loadB(it0 << 5, curB);

    for (int it = 0; it < nIt; ++it) {
        short8 vah, val, vbh, vbl;
        #pragma unroll
        for (int j = 0; j < 8; ++j) {
            uint ua = curA[j];
            vah[j] = (short)(ua & 0xffffu);
            val[j] = (short)(ua >> 16);
            if (PACKED) {
                uint ub = curB[j];
                vbh[j] = (short)(ub & 0xffffu);
                vbl[j] = (short)(ub >> 16);
            } else {
                float v = __uint_as_float(curB[j]);
                ushort h = f2bf(v);
                float hf = __uint_as_float((uint)h << 16);
                vbh[j] = (short)h;
                vbl[j] = (short)f2bf(v - hf);
            }
        }
        __syncthreads();
        *(short8*)&Ah[aw] = vah;
        *(short8*)&Al[aw] = val;
        *(short8*)&Bh[bw] = vbh;
        *(short8*)&Bl[bw] = vbl;
        __syncthreads();

        if (it + 1 < nIt) {
            loadA((it0 + it + 1) << 5, nxtA);
            loadB((it0 + it + 1) << 5, nxtB);
        }

        short8 fah0 = *(const short8*)&Ah[a0];
        short8 fah1 = *(const short8*)&Ah[a1];
        short8 fal0 = *(const short8*)&Al[a0];
        short8 fal1 = *(const short8*)&Al[a1];
        short8 fbh0 = *(const short8*)&Bh[b0];
        short8 fbh1 = *(const short8*)&Bh[b1];
        short8 fbl0 = *(const short8*)&Bl[b0];
        short8 fbl1 = *(const short8*)&Bl[b1];

        acc[0][0] = __builtin_amdgcn_mfma_f32_16x16x32_bf16(fah0, fbh0, acc[0][0], 0, 0, 0);
        acc[0][1] = __builtin_amdgcn_mfma_f32_16x16x32_bf16(fah0, fbh1, acc[0][1], 0, 0, 0);
        acc[1][0] = __builtin_amdgcn_mfma_f32_16x16x32_bf16(fah1, fbh0, acc[1][0], 0, 0, 0);
        acc[1][1] = __builtin_amdgcn_mfma_f32_16x16x32_bf16(fah1, fbh1, acc[1][1], 0, 0, 0);
        acc[0][0] = __builtin_amdgcn_mfma_f32_16x16x32_bf16(fah0, fbl0, acc[0][0], 0, 0, 0);
        acc[0][1] = __builtin_amdgcn_mfma_f32_16x16x32_bf16(fah0, fbl1, acc[0][1], 0, 0, 0);
        acc[1][0] = __builtin_amdgcn_mfma_f32_16x16x32_bf16(fah1, fbl0, acc[1][0], 0, 0, 0);
        acc[1][1] = __builtin_amdgcn_mfma_f32_16x16x32_bf16(fah1, fbl1, acc[1][1], 0, 0, 0);
        acc[0][0] = __builtin_amdgcn_mfma_f32_16x16x32_bf16(fal0, fbh0, acc[0][0], 0, 0, 0);
        acc[0][1] = __builtin_amdgcn_mfma_f32_16x16x32_bf16(fal0, fbh1, acc[0][1], 0, 0, 0);
        acc[1][0] = __builtin_amdgcn_mfma_f32_16x16x32_bf16(fal1, fbh0, acc[1][0], 0, 0, 0);
        acc[1][1] = __builtin_amdgcn_mfma_f32_16x16x32_bf16(fal1, fbh1, acc[1][1], 0, 0, 0);

        #pragma unroll
        for (int j = 0; j < 8; ++j) { curA[j] = nxtA[j]; curB[j] = nxtB[j]; }
    }

    if (gridDim.z > 1) {
        float* P = Pout + (size_t)z * B_N * N;
        #pragma unroll
        for (int mi = 0; mi < 2; ++mi)
        #pragma unroll
        for (int ni = 0; ni < 2; ++ni)
        #pragma unroll
        for (int r = 0; r < 4; ++r) {
            int row = bm + wm + mi * 16 + lc * 4 + r;
            int col = bn + wn + ni * 16 + lm;
            if (col < N) P[row * N + col] = acc[mi][ni][r];
        }
        return;
    }

    #pragma unroll
    for (int mi = 0; mi < 2; ++mi)
    #pragma unroll
    for (int ni = 0; ni < 2; ++ni)
    #pragma unroll
    for (int r = 0; r < 4; ++r) {
        int row = bm + wm + mi * 16 + lc * 4 + r;
        int col = bn + wn + ni * 16 + lm;
        float v = acc[mi][ni][r];
        if (EPI == 0) {
            v += bias[col];
            v = (v > 0.f) ? v : 0.2f * v;
            ((uint*)Cout)[row * ldc + col] = pack_split(v);
        } else {
            if (col < N) {
                int o = col / MB_INT, kk = col - o * MB_INT;
                ((float*)Cout)[(o * B_N + row) * MROW + kk] = v;
            }
        }
    }
}

// ---------------- split-K epilogues -------------------------------------------
__global__ __launch_bounds__(256) void epi_pack_kernel(
    const float* __restrict__ P, const float* __restrict__ bias,
    uint* __restrict__ outp, int n4, int S)
{
    const int c4 = blockIdx.x * 64 + (threadIdx.x & 63);
    const int r  = blockIdx.y * 4 + (threadIdx.x >> 6);
    const int idx = r * n4 + c4;
    const float4* P4 = (const float4*)P;
    float4 v = P4[idx];
    for (int s = 1; s < S; ++s) {
        float4 w = P4[(size_t)s * B_N * n4 + idx];
        v.x += w.x; v.y += w.y; v.z += w.z; v.w += w.w;
    }
    float4 bb = ((const float4*)bias)[c4];
    v.x += bb.x; v.y += bb.y; v.z += bb.z; v.w += bb.w;
    v.x = (v.x > 0.f) ? v.x : 0.2f * v.x;
    v.y = (v.y > 0.f) ? v.y : 0.2f * v.y;
    v.z = (v.z > 0.f) ? v.z : 0.2f * v.z;
    v.w = (v.w > 0.f) ? v.w : 0.2f * v.w;
    uint4 o;
    o.x = pack_split(v.x); o.y = pack_split(v.y);
    o.z = pack_split(v.z); o.w = pack_split(v.w);
    ((uint4*)outp)[idx] = o;
}

__global__ __launch_bounds__(256) void epi_m2_kernel(
    const float* __restrict__ P, float* __restrict__ M2, int S)
{
    int i = blockIdx.x * 256 + threadIdx.x;   // < 1024*500
    if (i >= B_N * 500) return;
    int r = i / 500, c = i - r * 500;
    float v = P[i];
    for (int s = 1; s < S; ++s) v += P[(size_t)s * B_N * 500 + i];
    int o = c / MB_INT, k = c - o * MB_INT;
    M2[(o * B_N + r) * MROW + k] = v;
}

// ---------------- sign projections: Rproj[o][b][12] = sum_k (+-) M2[o][b][k] ---
// Fixed +-1 masks (compile-time). |a-b|_1 >= |<p,a> - <p,b>| for p in {+-1}^50.
__device__ __constant__ const unsigned long long PMASK[NPROJ] = {
    0x2B5F1E3A4B6C7DULL, 0x19D4A7C3E85B26ULL, 0x3E6A1D59F0B483ULL,
    0x07C2F8A135E9D6ULL, 0x2A94E6B7D01C3FULL, 0x35B8D2041A7E6CULL,
    0x1CE07B3F68A5D2ULL, 0x22F1A4C85D93E0ULL, 0x0B67D3E92C50F8ULL,
    0x38A0C5171E4B9DULL, 0x114E92F6A3D078ULL, 0x2D73B0E84F169AULL
};

template<int J0>
__device__ __forceinline__ void proj3(const float* __restrict__ row, float* s) {
    float s0 = 0.f, s1 = 0.f, s2 = 0.f;
    #pragma unroll
    for (int k = 0; k < MB_INT; ++k) {
        float v = row[k];
        if ((PMASK[J0]     >> k) & 1ULL) s0 -= v; else s0 += v;
        if ((PMASK[J0 + 4] >> k) & 1ULL) s1 -= v; else s1 += v;
        if ((PMASK[J0 + 8] >> k) & 1ULL) s2 -= v; else s2 += v;
    }
    s[0] = s0; s[1] = s1; s[2] = s2;
}

// grid (16 row-tiles, 10 o), block 256: thread t -> row t&63, j0 = t>>6 (0..3)
__global__ __launch_bounds__(256) void proj_kernel(
    const float* __restrict__ M2, float* __restrict__ Rproj)
{
    __shared__ float Ls[64 * 53];
    const int rt = blockIdx.x, o = blockIdx.y, t = threadIdx.x;

    #pragma unroll
    for (int i = 0; i < 13; ++i) {
        int idx = t + i * 256;                 // 64*52 = 3328 = 13*256
        int r = idx / 52, k = idx - r * 52;
        float v = (k < MB_INT) ? M2[(o * B_N + rt * 64 + r) * MROW + k] : 0.f;
        Ls[r * 53 + k] = v;
    }
    __syncthreads();

    const int r = t & 63, j0 = t >> 6;         // j0 wave-uniform
    float s[3];
    if      (j0 == 0) proj3<0>(&Ls[r * 53], s);
    else if (j0 == 1) proj3<1>(&Ls[r * 53], s);
    else if (j0 == 2) proj3<2>(&Ls[r * 53], s);
    else              proj3<3>(&Ls[r * 53], s);

    float* dst = Rproj + (size_t)(o * B_N + rt * 64 + r) * NPROJ;
    dst[j0] = s[0]; dst[j0 + 4] = s[1]; dst[j0 + 8] = s[2];
}

// ---------------- pairwise L1 + exp, projection-pruned -------------------------
// grid (4 Agrp, 10 o, 32 ch of 32 B-rows), block 256 (4 waves, one A-tile each).
// Prune: max_j |proj_a[j]-proj_b[j]| > 110 (exact lower bound of L1) ->
// exp underflows to +0.0f. Fallback (rare): full row, wave-uniform broadcast
// loads from global. Self term pre-added (1.0), excluded from vote/fallback.
__global__ __launch_bounds__(256) void pairwise_kernel(
    const float* __restrict__ M2, const float* __restrict__ Rproj,
    float* __restrict__ part)
{
    __shared__ float Lp[32 * NPROJ];
    const int grp = blockIdx.x, o = blockIdx.y, ch = blockIdx.z;
    const int t = threadIdx.x, wid = t >> 6, lane = t & 63;

    if (t < 96)
        ((float4*)Lp)[t] = ((const float4*)(Rproj + (size_t)(o * B_N + ch * 32) * NPROJ))[t];
    __syncthreads();

    const int b = (grp * 4 + wid) * 64 + lane;

    // own full row in registers
    const float4* Ar = (const float4*)(M2 + (size_t)(o * B_N + b) * MROW);
    float4 A0 = Ar[0], A1 = Ar[1], A2 = Ar[2],  A3 = Ar[3];
    float4 A4 = Ar[4], A5 = Ar[5], A6 = Ar[6],  A7 = Ar[7];
    float4 A8 = Ar[8], A9 = Ar[9], A10 = Ar[10], A11 = Ar[11];
    float2 A12 = *(const float2*)((const float*)Ar + 48);

    // own projections
    const float4* Pr = (const float4*)(Rproj + (size_t)(o * B_N + b) * NPROJ);
    float4 P0 = Pr[0], P1 = Pr[1], P2 = Pr[2];

    const int selfstep = (ch == (b >> 5)) ? (b & 31) : -1;
    float acc = (selfstep >= 0) ? 1.f : 0.f;   // self term exp(0)=1

    const float* Bbase = M2 + (size_t)(o * B_N + ch * 32) * MROW;

    for (int b2 = 0; b2 < 32; ++b2) {
        const float4* qp = (const float4*)&Lp[b2 * NPROJ];   // uniform -> bcast
        float4 q0 = qp[0], q1 = qp[1], q2 = qp[2];
        float d0 = fabsf(P0.x - q0.x), d1 = fabsf(P0.y - q0.y);
        float d2 = fabsf(P0.z - q0.z), d3 = fabsf(P0.w - q0.w);
        float d4 = fabsf(P1.x - q1.x), d5 = fabsf(P1.y - q1.y);
        float d6 = fabsf(P1.z - q1.z), d7 = fabsf(P1.w - q1.w);
        float d8 = fabsf(P2.x - q2.x), d9 = fabsf(P2.y - q2.y);
        float dA = fabsf(P2.z - q2.z), dB = fabsf(P2.w - q2.w);
        float m0 = fmaxf(fmaxf(d0, d1), fmaxf(d2, d3));
        float m1 = fmaxf(fmaxf(d4, d5), fmaxf(d6, d7));
        float m2 = fmaxf(fmaxf(d8, d9), fmaxf(dA, dB));
        float dmax = fmaxf(fmaxf(m0, m1), m2);

        if (__all(dmax > 110.f || b2 == selfstep)) continue;

        // fallback: exact full distance, B row broadcast from global
        const float4* q = (const float4*)(Bbase + b2 * MROW);
        float4 s = {0.f, 0.f, 0.f, 0.f};
        float4 v;
        v = q[0];  s.x += fabsf(A0.x - v.x);  s.y += fabsf(A0.y - v.y);  s.z += fabsf(A0.z - v.z);  s.w += fabsf(A0.w - v.w);
        v = q[1];  s.x += fabsf(A1.x - v.x);  s.y += fabsf(A1.y - v.y);  s.z += fabsf(A1.z - v.z);  s.w += fabsf(A1.w - v.w);
        v = q[2];  s.x += fabsf(A2.x - v.x);  s.y += fabsf(A2.y - v.y);  s.z += fabsf(A2.z - v.z);  s.w += fabsf(A2.w - v.w);
        v = q[3];  s.x += fabsf(A3.x - v.x);  s.y += fabsf(A3.y - v.y);  s.z += fabsf(A3.z - v.z);  s.w += fabsf(A3.w - v.w);
        v = q[4];  s.x += fabsf(A4.x - v.x);  s.y += fabsf(A4.y - v.y);  s.z += fabsf(A4.z - v.z);  s.w += fabsf(A4.w - v.w);
        v = q[5];  s.x += fabsf(A5.x - v.x);  s.y += fabsf(A5.y - v.y);  s.z += fabsf(A5.z - v.z);  s.w += fabsf(A5.w - v.w);
        v = q[6];  s.x += fabsf(A6.x - v.x);  s.y += fabsf(A6.y - v.y);  s.z += fabsf(A6.z - v.z);  s.w += fabsf(A6.w - v.w);
        v = q[7];  s.x += fabsf(A7.x - v.x);  s.y += fabsf(A7.y - v.y);  s.z += fabsf(A7.z - v.z);  s.w += fabsf(A7.w - v.w);
        v = q[8];  s.x += fabsf(A8.x - v.x);  s.y += fabsf(A8.y - v.y);  s.z += fabsf(A8.z - v.z);  s.w += fabsf(A8.w - v.w);
        v = q[9];  s.x += fabsf(A9.x - v.x);  s.y += fabsf(A9.y - v.y);  s.z += fabsf(A9.z - v.z);  s.w += fabsf(A9.w - v.w);
        v = q[10]; s.x += fabsf(A10.x - v.x); s.y += fabsf(A10.y - v.y); s.z += fabsf(A10.z - v.z); s.w += fabsf(A10.w - v.w);
        v = q[11]; s.x += fabsf(A11.x - v.x); s.y += fabsf(A11.y - v.y); s.z += fabsf(A11.z - v.z); s.w += fabsf(A11.w - v.w);
        v = q[12]; s.x += fabsf(A12.x - v.x); s.y += fabsf(A12.y - v.y);
        float d = (s.x + s.y) + (s.z + s.w);
        float e = __expf(-d);
        acc += (b2 == selfstep) ? 0.f : e;
    }
    part[(ch * MB_OUT + o) * B_N + b] = acc;
}

// ---------------- reduce 32 partials into h0p[:, 315:325] ----------------------
__global__ __launch_bounds__(256) void mb_reduce_kernel(
    const float* __restrict__ part, uint* __restrict__ h0p)
{
    int i = blockIdx.x * 256 + threadIdx.x;
    if (i < MB_OUT * B_N) {
        int o = i / B_N, b = i - o * B_N;
        float s = 0.f;
        #pragma unroll
        for (int ch = 0; ch < 32; ++ch)
            s += part[(ch * MB_OUT + o) * B_N + b];
        h0p[b * H0_S + FEAT + o] = pack_split(s);
    }
}

// ---------------- final layer: sigmoid(h4 @ W5 + b5) ---------------------------
__global__ __launch_bounds__(256) void final_kernel(
    const uint* __restrict__ h4p, const float* __restrict__ W5,
    const float* __restrict__ b5, float* __restrict__ out)
{
    const int wave = threadIdx.x >> 6;
    const int lane = threadIdx.x & 63;
    const int row  = blockIdx.x * 4 + wave;

    const uint4  h = ((const uint4*)(h4p + row * 256))[lane];
    const float4 w = ((const float4*)W5)[lane];
    float s = unpack_split(h.x) * w.x + unpack_split(h.y) * w.y
            + unpack_split(h.z) * w.z + unpack_split(h.w) * w.w;
    #pragma unroll
    for (int off = 32; off > 0; off >>= 1)
        s += __shfl_xor(s, off);
    if (lane == 0) {
        float z = s + b5[0];
        out[row] = 1.f / (1.f + __expf(-z));
    }
}

// ---------------- launch -------------------------------------------------------
extern "C" void kernel_launch(void* const* d_in, const int* in_sizes, int n_in,
                              void* d_out, int out_size, void* d_ws, size_t ws_size,
                              hipStream_t stream)
{
    const float* ts   = (const float*)d_in[0];
    const int*   cond = (const int*)  d_in[1];
    const float* emb  = (const float*)d_in[2];
    const float* T    = (const float*)d_in[3];
    const float* W1   = (const float*)d_in[4];
    const float* b1   = (const float*)d_in[5];
    const float* W2   = (const float*)d_in[6];
    const float* b2   = (const float*)d_in[7];
    const float* W3   = (const float*)d_in[8];
    const float* b3   = (const float*)d_in[9];
    const float* W4   = (const float*)d_in[10];
    const float* b4   = (const float*)d_in[11];
    const float* W5   = (const float*)d_in[12];
    const float* b5   = (const float*)d_in[13];
    float* out = (float*)d_out;

    // workspace (4-byte units)
    uint*  h0p  = (uint*)d_ws;             // 1024*352   = 360448
    float* M2   = (float*)(h0p + 360448);  // 10*1024*64 = 655360
    uint*  h1p  = (uint*)(M2 + 655360);    // 1572864
    uint*  h2p  = h1p + 1572864;           // 1048576
    uint*  h3p  = (uint*)M2;               // alias (524288 <= 655360)
    uint*  h4p  = h1p;                     // alias
    float* part  = (float*)h1p;            // alias: 32*10*1024 = 327680 (dead before W1)
    float* Rproj = part + 327680;          // alias: 10240*12   = 122880 (dead before W1)
    const size_t baseU = 360448 + 655360 + 1572864 + 1048576;   // 3637248 (14.5MB)

    // packed weights (after base): T,W1,W2,W3,W4 contiguous
    uint* Wpk = (uint*)d_ws + baseU;
    uint* Tp  = Wpk;                       // 320*512   = 163840
    uint* W1p = Tp  + 163840;              // 352*1536  = 540672
    uint* W2p = W1p + 540672;              // 1536*1024 = 1572864
    uint* W3p = W2p + 1572864;             // 1024*512  = 524288
    uint* W4p = W3p + 524288;              // 512*256   = 131072
    const size_t packU = 2932736;
    const bool packed = (ws_size / 4) >= (baseU + packU);

    const size_t pbase = packed ? baseU + packU : baseU;
    size_t capU = (ws_size / 4 > pbase) ? ws_size / 4 - pbase : 0;
    float* Pbuf = (float*)((uint*)d_ws + pbase);

    auto fits = [&](int s, int N) { return (size_t)s * B_N * N <= capU; };
    const int ST = fits(2, 500)  ? 2 : 1;
    const int S1 = fits(2, 1536) ? 2 : 1;
    const int S2 = fits(3, 1024) ? 3 : (fits(2, 1024) ? 2 : 1);
    const int S3 = fits(4, 512)  ? 4 : (fits(2, 512)  ? 2 : 1);
    const int S4 = fits(4, 256)  ? 4 : (fits(2, 256)  ? 2 : 1);

    if (packed)
        pack_all_kernel<<<(2932736 + 255) / 256, 256, 0, stream>>>(T, W1, W2, W3, W4, Wpk);

    build_x_kernel<<<B_N, 320, 0, stream>>>(ts, cond, emb, h0p);

    // M = x @ T (K=315->320, N=500->512 packed)
    {
        int kit = 10, ks = (kit + ST - 1) / ST;
        dim3 g(8, 16, ST);
        if (packed)
            gemm_mfma<1,1><<<g, 256, 0, stream>>>(h0p, Tp, nullptr, M2,
                                                  500, FEAT, H0_S, 512, 0, kit, ks, Pbuf);
        else
            gemm_mfma<1,0><<<g, 256, 0, stream>>>(h0p, T, nullptr, M2,
                                                  500, FEAT, H0_S, 500, 0, kit, ks, Pbuf);
        if (ST > 1)
            epi_m2_kernel<<<(B_N * 500 + 255) / 256, 256, 0, stream>>>(Pbuf, M2, ST);
    }

    { dim3 g(16, MB_OUT); proj_kernel<<<g, 256, 0, stream>>>(M2, Rproj); }
    { dim3 g(4, MB_OUT, 32); pairwise_kernel<<<g, 256, 0, stream>>>(M2, Rproj, part); }
    mb_reduce_kernel<<<(MB_OUT * B_N + 255) / 256, 256, 0, stream>>>(part, h0p);

    auto runL = [&](const uint* in, const float* Wf, const uint* Wp,
                    const float* bia, uint* outp, int N, int K, int lda,
                    int kit, int ldbp, int S) {
        int ks = (kit + S - 1) / S;
        dim3 g(N / 64, 16, S);
        if (packed)
            gemm_mfma<0,1><<<g, 256, 0, stream>>>(in, Wp, bia, outp, N, K, lda, ldbp, N, kit, ks, Pbuf);
        else
            gemm_mfma<0,0><<<g, 256, 0, stream>>>(in, Wf, bia, outp, N, K, lda, N,  N, kit, ks, Pbuf);
        if (S > 1) {
            dim3 ge((N / 4) / 64, B_N / 4);
            epi_pack_kernel<<<ge, 256, 0, stream>>>(Pbuf, bia, outp, N / 4, S);
        }
    };

    runL(h0p, W1, W1p, b1, h1p, 1536, H0_W, H0_S, 11, 1536, S1);
    runL(h1p, W2, W2p, b2, h2p, 1024, 1536, 1536, 48, 1024, S2);
    runL(h2p, W3, W3p, b3, h3p,  512, 1024, 1024, 32,  512, S3);
    runL(h3p, W4, W4p, b4, h4p,  256,  512,  512, 16,  256, S4);

    final_kernel<<<B_N / 4, 256, 0, stream>>>(h4p, W5, b5, out);
}